// Round 9
// baseline (252.639 us; speedup 1.0000x reference)
//
#include <hip/hip_runtime.h>

typedef unsigned short u16;
typedef short bf16x8 __attribute__((ext_vector_type(8)));
typedef float f32x4 __attribute__((ext_vector_type(4)));
typedef float f32x16 __attribute__((ext_vector_type(16)));

namespace {

constexpr int kB = 2, kS = 2048, kD = 1024, kH = 16, kDh = 64;
constexpr float kC2 = 0.125f * 1.44269504088896341f;  // score scale * log2(e)

__device__ inline u16 f32_bf16(float f) {
    unsigned u = __float_as_uint(f);
    u += 0x7FFFu + ((u >> 16) & 1u);        // RNE
    return (u16)(u >> 16);
}

__device__ inline u16 f32_bf16_fast(float f) {   // round-half-up (cheap)
    return (u16)((__float_as_uint(f) + 0x8000u) >> 16);
}

__device__ inline float fast_exp2(float x) {     // raw v_exp_f32 (1 instr)
    float r;
    asm("v_exp_f32 %0, %1" : "=v"(r) : "v"(x));
    return r;
}

__device__ inline void gl_lds16(const void* g, void* l) {
    __builtin_amdgcn_global_load_lds(
        (const __attribute__((address_space(1))) void*)g,
        (__attribute__((address_space(3))) void*)l, 16, 0, 0);
}

__device__ inline int swz8(int l) {   // GEMM staging swizzle (u16 units)
    return ((l & 3) ^ ((l >> 2) & 3) ^ ((l >> 4) & 3)) * 8;
}

// ------- fused prep: fp32->bf16 convert (y<3) + weight transpose (y>=3) ----
// Wq (z==0) pre-scaled by kC2 so attention scores arrive exp2-ready.
__global__ __launch_bounds__(256) void prep(
    const float* __restrict__ s0, const float* __restrict__ s1,
    const float* __restrict__ s2,
    u16* __restrict__ d0, u16* __restrict__ d1, u16* __restrict__ d2,
    const float* __restrict__ W0, const float* __restrict__ W1,
    const float* __restrict__ W2, const float* __restrict__ W3,
    u16* __restrict__ T0, u16* __restrict__ T1,
    u16* __restrict__ T2, u16* __restrict__ T3)
{
    const int y = blockIdx.y;
    if (y < 3) {
        const float* src = y == 0 ? s0 : (y == 1 ? s1 : s2);
        u16* dst = y == 0 ? d0 : (y == 1 ? d1 : d2);
        const int i = blockIdx.x * 256 + threadIdx.x;
        const float4* s4 = (const float4*)src;
        float4 a = s4[2 * i], b = s4[2 * i + 1];
        uint4 o;
        o.x = (unsigned)f32_bf16(a.x) | ((unsigned)f32_bf16(a.y) << 16);
        o.y = (unsigned)f32_bf16(a.z) | ((unsigned)f32_bf16(a.w) << 16);
        o.z = (unsigned)f32_bf16(b.x) | ((unsigned)f32_bf16(b.y) << 16);
        o.w = (unsigned)f32_bf16(b.z) | ((unsigned)f32_bf16(b.w) << 16);
        ((uint4*)dst)[i] = o;
        return;
    }
    if (blockIdx.x >= 256) return;
    const int z = y - 3;
    const float* W = z == 0 ? W0 : (z == 1 ? W1 : (z == 2 ? W2 : W3));
    u16* Wt = z == 0 ? T0 : (z == 1 ? T1 : (z == 2 ? T2 : T3));
    const float sc = (z == 0) ? kC2 : 1.0f;

    __shared__ __attribute__((aligned(16))) u16 T[64][65];  // [k][n]
    const int t = threadIdx.x;
    const int n0 = (blockIdx.x & 15) * 64, k0 = (blockIdx.x >> 4) * 64;
    const int r = t >> 4, c4 = (t & 15) * 4;
#pragma unroll
    for (int it = 0; it < 4; ++it) {
        const int rr = r + 16 * it;
        float4 v = *(const float4*)(W + (size_t)(k0 + rr) * kD + n0 + c4);
        T[rr][c4 + 0] = f32_bf16(v.x * sc);
        T[rr][c4 + 1] = f32_bf16(v.y * sc);
        T[rr][c4 + 2] = f32_bf16(v.z * sc);
        T[rr][c4 + 3] = f32_bf16(v.w * sc);
    }
    __syncthreads();
#pragma unroll
    for (int it = 0; it < 4; ++it) {
        const int nn = r + 16 * it;
        uint2 pk;
        pk.x = (unsigned)T[c4 + 0][nn] | ((unsigned)T[c4 + 1][nn] << 16);
        pk.y = (unsigned)T[c4 + 2][nn] | ((unsigned)T[c4 + 3][nn] << 16);
        *(uint2*)(Wt + (size_t)(n0 + nn) * kD + k0 + c4) = pk;
    }
}

// --------- V transpose (bf16): V[b,s,1024] -> Vt[bh=32][dh=64][s=2048] -----
__global__ __launch_bounds__(256) void vtrans(
    const u16* __restrict__ V, u16* __restrict__ Vt)
{
    __shared__ __attribute__((aligned(16))) u16 T[64][65];  // [d][s]
    const int t = threadIdx.x;
    const int s0 = blockIdx.x * 64;
    const int bh = blockIdx.y, b = bh >> 4, h = bh & 15;
    const int rr = t >> 3, c0 = (t & 7) * 8;
    union { u16 u[8]; uint4 v4; } buf;
#pragma unroll
    for (int p = 0; p < 2; ++p) {
        const int s = rr + 32 * p;
        buf.v4 = *(const uint4*)(V + (size_t)(b * kS + s0 + s) * kD + h * kDh + c0);
#pragma unroll
        for (int i = 0; i < 8; ++i) T[c0 + i][s] = buf.u[i];
    }
    __syncthreads();
#pragma unroll
    for (int p = 0; p < 2; ++p) {
        const int d = rr + 32 * p;
#pragma unroll
        for (int i = 0; i < 8; ++i) buf.u[i] = T[d][c0 + i];
        *(uint4*)(Vt + (size_t)(bh * kDh + d) * kS + s0 + c0) = buf.v4;
    }
}

// ---- m97-style bf16 MFMA GEMM: C[M,N] = A[M,K] @ Wt[N,K]^T, 128x128 tile --
template <bool F32OUT>
__device__ inline void gemm128_body(
    const u16* __restrict__ A, const u16* __restrict__ Wt,
    void* __restrict__ Cout, int M, int N, int K, int bx, int by)
{
    __shared__ __attribute__((aligned(16))) u16 As[128 * 32];
    __shared__ __attribute__((aligned(16))) u16 Bs[128 * 32];
    const int t = threadIdx.x, w = t >> 6, l = t & 63;
    const int quad = l >> 4, c = l & 15;
    const int wm = w >> 1, wn = w & 1;
    const int m0 = by * 128, n0 = bx * 128;
    const int lr = l >> 2, lc = swz8(l);
    const int xc = ((quad ^ (c & 3) ^ ((c >> 2) & 3))) * 8;

    const u16* ga0 = A  + (size_t)(m0 + w * 32 + lr) * K + lc;
    const u16* ga1 = A  + (size_t)(m0 + w * 32 + 16 + lr) * K + lc;
    const u16* gb0 = Wt + (size_t)(n0 + w * 32 + lr) * K + lc;
    const u16* gb1 = Wt + (size_t)(n0 + w * 32 + 16 + lr) * K + lc;
    u16* la0 = &As[(w * 32) * 32];
    u16* la1 = &As[(w * 32 + 16) * 32];
    u16* lb0 = &Bs[(w * 32) * 32];
    u16* lb1 = &Bs[(w * 32 + 16) * 32];

    f32x4 acc[4][4];
#pragma unroll
    for (int mi = 0; mi < 4; ++mi)
#pragma unroll
        for (int nj = 0; nj < 4; ++nj) acc[mi][nj] = 0;

    for (int k0 = 0; k0 < K; k0 += 32) {
        gl_lds16(ga0 + k0, la0);
        gl_lds16(ga1 + k0, la1);
        gl_lds16(gb0 + k0, lb0);
        gl_lds16(gb1 + k0, lb1);
        __syncthreads();
        bf16x8 af[4], bf[4];
#pragma unroll
        for (int mi = 0; mi < 4; ++mi)
            af[mi] = *(const bf16x8*)&As[(wm * 64 + mi * 16 + c) * 32 + xc];
#pragma unroll
        for (int nj = 0; nj < 4; ++nj)
            bf[nj] = *(const bf16x8*)&Bs[(wn * 64 + nj * 16 + c) * 32 + xc];
#pragma unroll
        for (int mi = 0; mi < 4; ++mi)
#pragma unroll
            for (int nj = 0; nj < 4; ++nj)
                acc[mi][nj] = __builtin_amdgcn_mfma_f32_16x16x32_bf16(
                    af[mi], bf[nj], acc[mi][nj], 0, 0, 0);
        __syncthreads();
    }

#pragma unroll
    for (int mi = 0; mi < 4; ++mi)
#pragma unroll
        for (int nj = 0; nj < 4; ++nj)
#pragma unroll
            for (int r = 0; r < 4; ++r) {
                const size_t row = m0 + wm * 64 + mi * 16 + quad * 4 + r;
                const size_t col = n0 + wn * 64 + nj * 16 + c;
                if (F32OUT)
                    ((float*)Cout)[row * N + col] = acc[mi][nj][r];
                else
                    ((u16*)Cout)[row * N + col] = f32_bf16(acc[mi][nj][r]);
            }
}

__global__ __launch_bounds__(256) void gemm_qkv(
    const u16* __restrict__ A0, const u16* __restrict__ A1,
    const u16* __restrict__ A2,
    const u16* __restrict__ W0, const u16* __restrict__ W1,
    const u16* __restrict__ W2,
    u16* __restrict__ C0, u16* __restrict__ C1, u16* __restrict__ C2)
{
    const int z = blockIdx.z;
    const u16* A  = z == 0 ? A0 : (z == 1 ? A1 : A2);
    const u16* Wt = z == 0 ? W0 : (z == 1 ? W1 : W2);
    u16* C = z == 0 ? C0 : (z == 1 ? C1 : C2);
    gemm128_body<false>(A, Wt, C, kB * kS, kD, kD, blockIdx.x, blockIdx.y);
}

// ---- 64x128-tile GEMM for the output projection (512 blocks = 2/CU) -------
__global__ __launch_bounds__(256) void gemm_out(
    const u16* __restrict__ A, const u16* __restrict__ Wt,
    float* __restrict__ C)
{
    __shared__ __attribute__((aligned(16))) u16 As[64 * 32];
    __shared__ __attribute__((aligned(16))) u16 Bs[128 * 32];
    const int N = kD, K = kD;
    const int t = threadIdx.x, w = t >> 6, l = t & 63;
    const int quad = l >> 4, c = l & 15;
    const int wm = w >> 1, wn = w & 1;
    const int m0 = blockIdx.y * 64, n0 = blockIdx.x * 128;
    const int lr = l >> 2, lc = swz8(l);
    const int xc = ((quad ^ (c & 3) ^ ((c >> 2) & 3))) * 8;

    const u16* ga  = A  + (size_t)(m0 + w * 16 + lr) * K + lc;
    const u16* gb0 = Wt + (size_t)(n0 + w * 16 + lr) * K + lc;
    const u16* gb1 = Wt + (size_t)(n0 + 64 + w * 16 + lr) * K + lc;
    u16* la  = &As[(w * 16) * 32];
    u16* lb0 = &Bs[(w * 16) * 32];
    u16* lb1 = &Bs[(64 + w * 16) * 32];

    f32x4 acc[2][4];
#pragma unroll
    for (int mi = 0; mi < 2; ++mi)
#pragma unroll
        for (int nj = 0; nj < 4; ++nj) acc[mi][nj] = 0;

    for (int k0 = 0; k0 < K; k0 += 32) {
        gl_lds16(ga + k0, la);
        gl_lds16(gb0 + k0, lb0);
        gl_lds16(gb1 + k0, lb1);
        __syncthreads();
        bf16x8 af[2], bf[4];
#pragma unroll
        for (int mi = 0; mi < 2; ++mi)
            af[mi] = *(const bf16x8*)&As[(wm * 32 + mi * 16 + c) * 32 + xc];
#pragma unroll
        for (int nj = 0; nj < 4; ++nj)
            bf[nj] = *(const bf16x8*)&Bs[(wn * 64 + nj * 16 + c) * 32 + xc];
#pragma unroll
        for (int mi = 0; mi < 2; ++mi)
#pragma unroll
            for (int nj = 0; nj < 4; ++nj)
                acc[mi][nj] = __builtin_amdgcn_mfma_f32_16x16x32_bf16(
                    af[mi], bf[nj], acc[mi][nj], 0, 0, 0);
        __syncthreads();
    }

#pragma unroll
    for (int mi = 0; mi < 2; ++mi)
#pragma unroll
        for (int nj = 0; nj < 4; ++nj)
#pragma unroll
            for (int r = 0; r < 4; ++r) {
                const size_t row = m0 + wm * 32 + mi * 16 + quad * 4 + r;
                const size_t col = n0 + wn * 64 + nj * 16 + c;
                C[row * N + col] = acc[mi][nj][r];
            }
}

// ------- MFMA flash attention, 32x32x16, VGPR-staged software pipeline -----
// Block = 128 q-rows x (b,h); wave w owns q-rows w*32..+31. Key tiles of 64.
// Pipeline: global_load (tile t+1) -> VGPRs issued BEFORE compute of tile t
// (plain loads: no LDS alias hazard, compiler leaves them in flight), then
// read-barrier -> ds_write into the single K/V buffer -> publish-barrier.
// QPs: per-wave Q staging (prologue) reused as P scratch. 32 KB LDS total.
__global__ __launch_bounds__(256) void attn(
    const u16* __restrict__ Q, const u16* __restrict__ K,
    const u16* __restrict__ Vt, u16* __restrict__ AO)
{
    __shared__ __attribute__((aligned(16))) u16 KsL[64 * 64];      // [key][dh]
    __shared__ __attribute__((aligned(16))) u16 VtL[64 * 64];      // [d][key]
    __shared__ __attribute__((aligned(16))) u16 QPs[4 * 32 * 64];  // per-wave Q / P

    const int t = threadIdx.x, w = t >> 6, l = t & 63;
    const int half = l >> 5, m = l & 31;      // fragment coords
    const int q0 = blockIdx.x * 128;
    const int bh = blockIdx.y, b = bh >> 4, h = bh & 15;
    const int sl = l >> 3;                    // staging row within 8-row group
    const int sc = (l & 7) ^ sl;              // staging global chunk (swizzled)
    const int cc = l & 7;                     // LDS chunk
    const int R0w = w * 16;                   // this wave's staging rows

    const size_t kbase = (size_t)(b * kS) * kD + h * kDh;
    const size_t vbase = (size_t)bh * kDh * kS;
    const size_t qbase = (size_t)(b * kS + q0 + w * 32) * kD + h * kDh;

    // ---- prologue: Q via gl_lds; K/V tile 0 via regs + ds_write
#pragma unroll
    for (int i = 0; i < 4; ++i)
        gl_lds16(Q + qbase + (size_t)(i * 8 + sl) * kD + sc * 8,
                 &QPs[w * 2048 + i * 512]);

    uint4 kreg[2], vreg[2];
#pragma unroll
    for (int i = 0; i < 2; ++i) {
        kreg[i] = *(const uint4*)(K + kbase + (size_t)(R0w + i * 8 + sl) * kD + sc * 8);
        vreg[i] = *(const uint4*)(Vt + vbase + (size_t)(R0w + i * 8 + sl) * kS + sc * 8);
    }
#pragma unroll
    for (int i = 0; i < 2; ++i) {
        *(uint4*)&KsL[(R0w + i * 8 + sl) * 64 + cc * 8] = kreg[i];
        *(uint4*)&VtL[(R0w + i * 8 + sl) * 64 + cc * 8] = vreg[i];
    }
    __syncthreads();

    bf16x8 qf[4];
#pragma unroll
    for (int ch = 0; ch < 4; ++ch)
        qf[ch] = *(const bf16x8*)
            &QPs[w * 2048 + m * 64 + ((2 * ch + half) ^ (m & 7)) * 8];

    bf16x8 ones;
#pragma unroll
    for (int i = 0; i < 8; ++i) ones[i] = (short)0x3F80;

    f32x16 o0 = 0, o1 = 0, ol = 0;
    constexpr int NT = kS / 64;

    for (int kt = 0; kt < NT; ++kt) {
        // ---- issue next tile's global loads (land during compute)
        if (kt + 1 < NT) {
#pragma unroll
            for (int i = 0; i < 2; ++i) {
                kreg[i] = *(const uint4*)
                    (K + kbase + (size_t)((kt + 1) * 64 + R0w + i * 8 + sl) * kD + sc * 8);
                vreg[i] = *(const uint4*)
                    (Vt + vbase + (size_t)(R0w + i * 8 + sl) * kS + (kt + 1) * 64 + sc * 8);
            }
        }

        // ---- S = Qc2 K^T : two 32x32 key-subtiles, 4 k-chains each
        f32x16 s0 = 0, s1 = 0;
#pragma unroll
        for (int ch = 0; ch < 4; ++ch) {
            const int xo = ((2 * ch + half) ^ (m & 7)) * 8;
            const bf16x8 kf0 = *(const bf16x8*)&KsL[(m) * 64 + xo];
            const bf16x8 kf1 = *(const bf16x8*)&KsL[(32 + m) * 64 + xo];
            s0 = __builtin_amdgcn_mfma_f32_32x32x16_bf16(qf[ch], kf0, s0, 0, 0, 0);
            s1 = __builtin_amdgcn_mfma_f32_32x32x16_bf16(qf[ch], kf1, s1, 0, 0, 0);
        }

        // ---- p = exp2(s) -> bf16 -> P (swizzled, wave-private)
#pragma unroll
        for (int reg = 0; reg < 16; ++reg) {
            const int qrow = (reg & 3) + 8 * (reg >> 2) + 4 * half;
            const int base = w * 2048 + qrow * 64;
            const int sw = (qrow & 7);
            {
                const int key = m;               // subtile 0
                QPs[base + ((key >> 3) ^ sw) * 8 + (key & 7)] =
                    f32_bf16_fast(fast_exp2(s0[reg]));
            }
            {
                const int key = 32 + m;          // subtile 1
                QPs[base + ((key >> 3) ^ sw) * 8 + (key & 7)] =
                    f32_bf16_fast(fast_exp2(s1[reg]));
            }
        }

        // ---- O += P @ V ; l += P @ ones   (P wave-private: no barrier)
#pragma unroll
        for (int ch = 0; ch < 4; ++ch) {
            const int xo = ((2 * ch + half) ^ (m & 7)) * 8;
            const bf16x8 pf = *(const bf16x8*)&QPs[w * 2048 + m * 64 + xo];
            const bf16x8 vf0 = *(const bf16x8*)&VtL[(m) * 64 + xo];
            const bf16x8 vf1 = *(const bf16x8*)&VtL[(32 + m) * 64 + xo];
            o0 = __builtin_amdgcn_mfma_f32_32x32x16_bf16(pf, vf0, o0, 0, 0, 0);
            o1 = __builtin_amdgcn_mfma_f32_32x32x16_bf16(pf, vf1, o1, 0, 0, 0);
            ol = __builtin_amdgcn_mfma_f32_32x32x16_bf16(pf, ones, ol, 0, 0, 0);
        }

        // ---- rotate the single buffer: all waves done reading, then write
        if (kt + 1 < NT) {
            __syncthreads();
#pragma unroll
            for (int i = 0; i < 2; ++i) {
                *(uint4*)&KsL[(R0w + i * 8 + sl) * 64 + cc * 8] = kreg[i];
                *(uint4*)&VtL[(R0w + i * 8 + sl) * 64 + cc * 8] = vreg[i];
            }
            __syncthreads();
        }
    }

    // ---- epilogue: O/l -> bf16 AO[b,s,1024]
    const size_t obase = (size_t)(b * kS + q0 + w * 32) * kD + h * kDh;
#pragma unroll
    for (int reg = 0; reg < 16; ++reg) {
        const int qrow = (reg & 3) + 8 * (reg >> 2) + 4 * half;
        const float inv = 1.0f / ol[reg];
        AO[obase + (size_t)qrow * kD + m]      = f32_bf16(o0[reg] * inv);
        AO[obase + (size_t)qrow * kD + 32 + m] = f32_bf16(o1[reg] * inv);
    }
}

}  // namespace

extern "C" void kernel_launch(void* const* d_in, const int* in_sizes, int n_in,
                              void* d_out, int out_size, void* d_ws, size_t ws_size,
                              hipStream_t stream)
{
    const float* q_in = (const float*)d_in[0];
    const float* k_in = (const float*)d_in[1];
    const float* v_in = (const float*)d_in[2];
    const float* Wq   = (const float*)d_in[3];
    const float* Wk   = (const float*)d_in[4];
    const float* Wv   = (const float*)d_in[5];
    const float* Wo   = (const float*)d_in[6];

    u16* ws = (u16*)d_ws;
    const size_t M1 = 1u << 20;
    u16* xq  = ws;             // later reused as Vt_g (dead after QKV GEMMs)
    u16* xk  = ws + 4 * M1;
    u16* xv  = ws + 8 * M1;
    u16* Wtq = ws + 12 * M1;
    u16* Wtk = ws + 13 * M1;
    u16* Wtv = ws + 14 * M1;
    u16* Wto = ws + 15 * M1;
    u16* Qp  = ws + 16 * M1;
    u16* Kp  = ws + 20 * M1;
    u16* Vp  = ws + 24 * M1;
    u16* AO  = ws + 28 * M1;
    u16* Vtg = xq;

    hipLaunchKernelGGL(prep, dim3(2048, 7), dim3(256), 0, stream,
                       q_in, k_in, v_in, xq, xk, xv,
                       Wq, Wk, Wv, Wo, Wtq, Wtk, Wtv, Wto);

    hipLaunchKernelGGL(gemm_qkv, dim3(8, 32, 3), dim3(256), 0, stream,
                       xq, xk, xv, Wtq, Wtk, Wtv, Qp, Kp, Vp);

    hipLaunchKernelGGL(vtrans, dim3(32, 32), dim3(256), 0, stream, Vp, Vtg);

    hipLaunchKernelGGL(attn, dim3(16, 32), dim3(256), 0, stream, Qp, Kp, Vtg, AO);

    hipLaunchKernelGGL(gemm_out, dim3(8, 64), dim3(256), 0, stream,
                       AO, Wto, (float*)d_out);
}

// Round 10
// 246.667 us; speedup vs baseline: 1.0242x; 1.0242x over previous
//
#include <hip/hip_runtime.h>

typedef unsigned short u16;
typedef short bf16x8 __attribute__((ext_vector_type(8)));
typedef float f32x4 __attribute__((ext_vector_type(4)));
typedef float f32x16 __attribute__((ext_vector_type(16)));

namespace {

constexpr int kB = 2, kS = 2048, kD = 1024, kH = 16, kDh = 64;
constexpr float kC2 = 0.125f * 1.44269504088896341f;  // score scale * log2(e)

__device__ inline u16 f32_bf16(float f) {
    unsigned u = __float_as_uint(f);
    u += 0x7FFFu + ((u >> 16) & 1u);        // RNE
    return (u16)(u >> 16);
}

__device__ inline u16 f32_bf16_fast(float f) {   // round-half-up (cheap)
    return (u16)((__float_as_uint(f) + 0x8000u) >> 16);
}

__device__ inline float fast_exp2(float x) {     // raw v_exp_f32 (1 instr)
    float r;
    asm("v_exp_f32 %0, %1" : "=v"(r) : "v"(x));
    return r;
}

__device__ inline void gl_lds16(const void* g, void* l) {
    __builtin_amdgcn_global_load_lds(
        (const __attribute__((address_space(1))) void*)g,
        (__attribute__((address_space(3))) void*)l, 16, 0, 0);
}

__device__ inline int swz8(int l) {   // GEMM staging swizzle (u16 units)
    return ((l & 3) ^ ((l >> 2) & 3) ^ ((l >> 4) & 3)) * 8;
}

// ------- fused prep: fp32->bf16 convert (y<3) + weight transpose (y>=3) ----
// Wq (z==0) pre-scaled by kC2 so attention scores arrive exp2-ready.
__global__ __launch_bounds__(256) void prep(
    const float* __restrict__ s0, const float* __restrict__ s1,
    const float* __restrict__ s2,
    u16* __restrict__ d0, u16* __restrict__ d1, u16* __restrict__ d2,
    const float* __restrict__ W0, const float* __restrict__ W1,
    const float* __restrict__ W2, const float* __restrict__ W3,
    u16* __restrict__ T0, u16* __restrict__ T1,
    u16* __restrict__ T2, u16* __restrict__ T3)
{
    const int y = blockIdx.y;
    if (y < 3) {
        const float* src = y == 0 ? s0 : (y == 1 ? s1 : s2);
        u16* dst = y == 0 ? d0 : (y == 1 ? d1 : d2);
        const int i = blockIdx.x * 256 + threadIdx.x;
        const float4* s4 = (const float4*)src;
        float4 a = s4[2 * i], b = s4[2 * i + 1];
        uint4 o;
        o.x = (unsigned)f32_bf16(a.x) | ((unsigned)f32_bf16(a.y) << 16);
        o.y = (unsigned)f32_bf16(a.z) | ((unsigned)f32_bf16(a.w) << 16);
        o.z = (unsigned)f32_bf16(b.x) | ((unsigned)f32_bf16(b.y) << 16);
        o.w = (unsigned)f32_bf16(b.z) | ((unsigned)f32_bf16(b.w) << 16);
        ((uint4*)dst)[i] = o;
        return;
    }
    if (blockIdx.x >= 256) return;
    const int z = y - 3;
    const float* W = z == 0 ? W0 : (z == 1 ? W1 : (z == 2 ? W2 : W3));
    u16* Wt = z == 0 ? T0 : (z == 1 ? T1 : (z == 2 ? T2 : T3));
    const float sc = (z == 0) ? kC2 : 1.0f;

    __shared__ __attribute__((aligned(16))) u16 T[64][65];  // [k][n]
    const int t = threadIdx.x;
    const int n0 = (blockIdx.x & 15) * 64, k0 = (blockIdx.x >> 4) * 64;
    const int r = t >> 4, c4 = (t & 15) * 4;
#pragma unroll
    for (int it = 0; it < 4; ++it) {
        const int rr = r + 16 * it;
        float4 v = *(const float4*)(W + (size_t)(k0 + rr) * kD + n0 + c4);
        T[rr][c4 + 0] = f32_bf16(v.x * sc);
        T[rr][c4 + 1] = f32_bf16(v.y * sc);
        T[rr][c4 + 2] = f32_bf16(v.z * sc);
        T[rr][c4 + 3] = f32_bf16(v.w * sc);
    }
    __syncthreads();
#pragma unroll
    for (int it = 0; it < 4; ++it) {
        const int nn = r + 16 * it;
        uint2 pk;
        pk.x = (unsigned)T[c4 + 0][nn] | ((unsigned)T[c4 + 1][nn] << 16);
        pk.y = (unsigned)T[c4 + 2][nn] | ((unsigned)T[c4 + 3][nn] << 16);
        *(uint2*)(Wt + (size_t)(n0 + nn) * kD + k0 + c4) = pk;
    }
}

// --------- V transpose (bf16): V[b,s,1024] -> Vt[bh=32][dh=64][s=2048] -----
__global__ __launch_bounds__(256) void vtrans(
    const u16* __restrict__ V, u16* __restrict__ Vt)
{
    __shared__ __attribute__((aligned(16))) u16 T[64][65];  // [d][s]
    const int t = threadIdx.x;
    const int s0 = blockIdx.x * 64;
    const int bh = blockIdx.y, b = bh >> 4, h = bh & 15;
    const int rr = t >> 3, c0 = (t & 7) * 8;
    union { u16 u[8]; uint4 v4; } buf;
#pragma unroll
    for (int p = 0; p < 2; ++p) {
        const int s = rr + 32 * p;
        buf.v4 = *(const uint4*)(V + (size_t)(b * kS + s0 + s) * kD + h * kDh + c0);
#pragma unroll
        for (int i = 0; i < 8; ++i) T[c0 + i][s] = buf.u[i];
    }
    __syncthreads();
#pragma unroll
    for (int p = 0; p < 2; ++p) {
        const int d = rr + 32 * p;
#pragma unroll
        for (int i = 0; i < 8; ++i) buf.u[i] = T[d][c0 + i];
        *(uint4*)(Vt + (size_t)(bh * kDh + d) * kS + s0 + c0) = buf.v4;
    }
}

// ---- m97-style bf16 MFMA GEMM: C[M,N] = A[M,K] @ Wt[N,K]^T, 128x128 tile --
template <bool F32OUT>
__device__ inline void gemm128_body(
    const u16* __restrict__ A, const u16* __restrict__ Wt,
    void* __restrict__ Cout, int M, int N, int K, int bx, int by)
{
    __shared__ __attribute__((aligned(16))) u16 As[128 * 32];
    __shared__ __attribute__((aligned(16))) u16 Bs[128 * 32];
    const int t = threadIdx.x, w = t >> 6, l = t & 63;
    const int quad = l >> 4, c = l & 15;
    const int wm = w >> 1, wn = w & 1;
    const int m0 = by * 128, n0 = bx * 128;
    const int lr = l >> 2, lc = swz8(l);
    const int xc = ((quad ^ (c & 3) ^ ((c >> 2) & 3))) * 8;

    const u16* ga0 = A  + (size_t)(m0 + w * 32 + lr) * K + lc;
    const u16* ga1 = A  + (size_t)(m0 + w * 32 + 16 + lr) * K + lc;
    const u16* gb0 = Wt + (size_t)(n0 + w * 32 + lr) * K + lc;
    const u16* gb1 = Wt + (size_t)(n0 + w * 32 + 16 + lr) * K + lc;
    u16* la0 = &As[(w * 32) * 32];
    u16* la1 = &As[(w * 32 + 16) * 32];
    u16* lb0 = &Bs[(w * 32) * 32];
    u16* lb1 = &Bs[(w * 32 + 16) * 32];

    f32x4 acc[4][4];
#pragma unroll
    for (int mi = 0; mi < 4; ++mi)
#pragma unroll
        for (int nj = 0; nj < 4; ++nj) acc[mi][nj] = 0;

    for (int k0 = 0; k0 < K; k0 += 32) {
        gl_lds16(ga0 + k0, la0);
        gl_lds16(ga1 + k0, la1);
        gl_lds16(gb0 + k0, lb0);
        gl_lds16(gb1 + k0, lb1);
        __syncthreads();
        bf16x8 af[4], bf[4];
#pragma unroll
        for (int mi = 0; mi < 4; ++mi)
            af[mi] = *(const bf16x8*)&As[(wm * 64 + mi * 16 + c) * 32 + xc];
#pragma unroll
        for (int nj = 0; nj < 4; ++nj)
            bf[nj] = *(const bf16x8*)&Bs[(wn * 64 + nj * 16 + c) * 32 + xc];
#pragma unroll
        for (int mi = 0; mi < 4; ++mi)
#pragma unroll
            for (int nj = 0; nj < 4; ++nj)
                acc[mi][nj] = __builtin_amdgcn_mfma_f32_16x16x32_bf16(
                    af[mi], bf[nj], acc[mi][nj], 0, 0, 0);
        __syncthreads();
    }

#pragma unroll
    for (int mi = 0; mi < 4; ++mi)
#pragma unroll
        for (int nj = 0; nj < 4; ++nj)
#pragma unroll
            for (int r = 0; r < 4; ++r) {
                const size_t row = m0 + wm * 64 + mi * 16 + quad * 4 + r;
                const size_t col = n0 + wn * 64 + nj * 16 + c;
                if (F32OUT)
                    ((float*)Cout)[row * N + col] = acc[mi][nj][r];
                else
                    ((u16*)Cout)[row * N + col] = f32_bf16(acc[mi][nj][r]);
            }
}

__global__ __launch_bounds__(256) void gemm_qkv(
    const u16* __restrict__ A0, const u16* __restrict__ A1,
    const u16* __restrict__ A2,
    const u16* __restrict__ W0, const u16* __restrict__ W1,
    const u16* __restrict__ W2,
    u16* __restrict__ C0, u16* __restrict__ C1, u16* __restrict__ C2)
{
    const int z = blockIdx.z;
    const u16* A  = z == 0 ? A0 : (z == 1 ? A1 : A2);
    const u16* Wt = z == 0 ? W0 : (z == 1 ? W1 : W2);
    u16* C = z == 0 ? C0 : (z == 1 ? C1 : C2);
    gemm128_body<false>(A, Wt, C, kB * kS, kD, kD, blockIdx.x, blockIdx.y);
}

// ---- 64x128-tile GEMM for the output projection (512 blocks = 2/CU) -------
__global__ __launch_bounds__(256) void gemm_out(
    const u16* __restrict__ A, const u16* __restrict__ Wt,
    float* __restrict__ C)
{
    __shared__ __attribute__((aligned(16))) u16 As[64 * 32];
    __shared__ __attribute__((aligned(16))) u16 Bs[128 * 32];
    const int N = kD, K = kD;
    const int t = threadIdx.x, w = t >> 6, l = t & 63;
    const int quad = l >> 4, c = l & 15;
    const int wm = w >> 1, wn = w & 1;
    const int m0 = blockIdx.y * 64, n0 = blockIdx.x * 128;
    const int lr = l >> 2, lc = swz8(l);
    const int xc = ((quad ^ (c & 3) ^ ((c >> 2) & 3))) * 8;

    const u16* ga  = A  + (size_t)(m0 + w * 16 + lr) * K + lc;
    const u16* gb0 = Wt + (size_t)(n0 + w * 16 + lr) * K + lc;
    const u16* gb1 = Wt + (size_t)(n0 + 64 + w * 16 + lr) * K + lc;
    u16* la  = &As[(w * 16) * 32];
    u16* lb0 = &Bs[(w * 16) * 32];
    u16* lb1 = &Bs[(64 + w * 16) * 32];

    f32x4 acc[2][4];
#pragma unroll
    for (int mi = 0; mi < 2; ++mi)
#pragma unroll
        for (int nj = 0; nj < 4; ++nj) acc[mi][nj] = 0;

    for (int k0 = 0; k0 < K; k0 += 32) {
        gl_lds16(ga + k0, la);
        gl_lds16(gb0 + k0, lb0);
        gl_lds16(gb1 + k0, lb1);
        __syncthreads();
        bf16x8 af[2], bf[4];
#pragma unroll
        for (int mi = 0; mi < 2; ++mi)
            af[mi] = *(const bf16x8*)&As[(wm * 32 + mi * 16 + c) * 32 + xc];
#pragma unroll
        for (int nj = 0; nj < 4; ++nj)
            bf[nj] = *(const bf16x8*)&Bs[(wn * 64 + nj * 16 + c) * 32 + xc];
#pragma unroll
        for (int mi = 0; mi < 2; ++mi)
#pragma unroll
            for (int nj = 0; nj < 4; ++nj)
                acc[mi][nj] = __builtin_amdgcn_mfma_f32_16x16x32_bf16(
                    af[mi], bf[nj], acc[mi][nj], 0, 0, 0);
        __syncthreads();
    }

#pragma unroll
    for (int mi = 0; mi < 2; ++mi)
#pragma unroll
        for (int nj = 0; nj < 4; ++nj)
#pragma unroll
            for (int r = 0; r < 4; ++r) {
                const size_t row = m0 + wm * 32 + mi * 16 + quad * 4 + r;
                const size_t col = n0 + wn * 64 + nj * 16 + c;
                C[row * N + col] = acc[mi][nj][r];
            }
}

// ------- MFMA flash attention: single-wave blocks, barrier-free ------------
// 64-thread block = 1 wave owning 32 q-rows of one (b,h). Grid 2048 blocks
// (8 blocks/CU; 20 KB LDS each). No __syncthreads anywhere — wave-synchronous
// with an explicit s_waitcnt vmcnt(0) after each gl_lds staging burst. 8
// independent waves per CU stagger their stage/exp/MFMA phases, overlapping
// the LDS, VALU, and MFMA pipes that a barriered multi-wave block serializes.
// LDS rows 64 u16 (128 B); chunk XOR-swizzled by (row&7). Q pre-scaled by
// kC2 so p = exp2(s). Row-normalizer l via MFMA against all-ones B.
__global__ __launch_bounds__(64) void attn(
    const u16* __restrict__ Q, const u16* __restrict__ K,
    const u16* __restrict__ Vt, u16* __restrict__ AO)
{
    __shared__ __attribute__((aligned(16))) u16 KsL[64 * 64];  // [key][dh]
    __shared__ __attribute__((aligned(16))) u16 VtL[64 * 64];  // [d][key]
    __shared__ __attribute__((aligned(16))) u16 QPs[32 * 64];  // Q staging, then P

    const int l = threadIdx.x;
    const int half = l >> 5, m = l & 31;      // fragment coords
    const int q0 = blockIdx.x * 32;
    const int bh = blockIdx.y, b = bh >> 4, h = bh & 15;
    const int sl = l >> 3;                    // staging row within 8-row group
    const int sc = (l & 7) ^ sl;              // staging global chunk (swizzled)

    const size_t kbase = (size_t)(b * kS) * kD + h * kDh;
    const size_t vbase = (size_t)bh * kDh * kS;
    const size_t qbase = (size_t)(b * kS + q0) * kD + h * kDh;

    // ---- stage Q (32 rows x 64 dh), swizzled; then hoist to registers
#pragma unroll
    for (int i = 0; i < 4; ++i)
        gl_lds16(Q + qbase + (size_t)(i * 8 + sl) * kD + sc * 8, &QPs[i * 512]);
    asm volatile("s_waitcnt vmcnt(0)" ::: "memory");

    bf16x8 qf[4];
#pragma unroll
    for (int ch = 0; ch < 4; ++ch)
        qf[ch] = *(const bf16x8*)&QPs[m * 64 + ((2 * ch + half) ^ (m & 7)) * 8];

    bf16x8 ones;
#pragma unroll
    for (int i = 0; i < 8; ++i) ones[i] = (short)0x3F80;

    f32x16 o0 = 0, o1 = 0, ol = 0;
    constexpr int NT = kS / 64;

    for (int kt = 0; kt < NT; ++kt) {
        // ---- stage this tile's K [64 key][64 dh] and Vt [64 d][64 key]
#pragma unroll
        for (int i = 0; i < 8; ++i) {
            gl_lds16(K + kbase + (size_t)(kt * 64 + i * 8 + sl) * kD + sc * 8,
                     &KsL[i * 512]);
            gl_lds16(Vt + vbase + (size_t)(i * 8 + sl) * kS + kt * 64 + sc * 8,
                     &VtL[i * 512]);
        }
        asm volatile("s_waitcnt vmcnt(0)" ::: "memory");

        // ---- S = Qc2 K^T : two 32x32 key-subtiles, 4 k-chains each
        f32x16 s0 = 0, s1 = 0;
#pragma unroll
        for (int ch = 0; ch < 4; ++ch) {
            const int xo = ((2 * ch + half) ^ (m & 7)) * 8;
            const bf16x8 kf0 = *(const bf16x8*)&KsL[(m) * 64 + xo];
            const bf16x8 kf1 = *(const bf16x8*)&KsL[(32 + m) * 64 + xo];
            s0 = __builtin_amdgcn_mfma_f32_32x32x16_bf16(qf[ch], kf0, s0, 0, 0, 0);
            s1 = __builtin_amdgcn_mfma_f32_32x32x16_bf16(qf[ch], kf1, s1, 0, 0, 0);
        }

        // ---- p = exp2(s) -> bf16 -> P (swizzled, wave-private)
#pragma unroll
        for (int reg = 0; reg < 16; ++reg) {
            const int qrow = (reg & 3) + 8 * (reg >> 2) + 4 * half;
            const int base = qrow * 64;
            const int sw = (qrow & 7);
            {
                const int key = m;               // subtile 0
                QPs[base + ((key >> 3) ^ sw) * 8 + (key & 7)] =
                    f32_bf16_fast(fast_exp2(s0[reg]));
            }
            {
                const int key = 32 + m;          // subtile 1
                QPs[base + ((key >> 3) ^ sw) * 8 + (key & 7)] =
                    f32_bf16_fast(fast_exp2(s1[reg]));
            }
        }

        // ---- O += P @ V ; l += P @ ones
#pragma unroll
        for (int ch = 0; ch < 4; ++ch) {
            const int xo = ((2 * ch + half) ^ (m & 7)) * 8;
            const bf16x8 pf = *(const bf16x8*)&QPs[m * 64 + xo];
            const bf16x8 vf0 = *(const bf16x8*)&VtL[(m) * 64 + xo];
            const bf16x8 vf1 = *(const bf16x8*)&VtL[(32 + m) * 64 + xo];
            o0 = __builtin_amdgcn_mfma_f32_32x32x16_bf16(pf, vf0, o0, 0, 0, 0);
            o1 = __builtin_amdgcn_mfma_f32_32x32x16_bf16(pf, vf1, o1, 0, 0, 0);
            ol = __builtin_amdgcn_mfma_f32_32x32x16_bf16(pf, ones, ol, 0, 0, 0);
        }
    }

    // ---- epilogue: O/l -> bf16 AO[b,s,1024]
    const size_t obase = (size_t)(b * kS + q0) * kD + h * kDh;
#pragma unroll
    for (int reg = 0; reg < 16; ++reg) {
        const int qrow = (reg & 3) + 8 * (reg >> 2) + 4 * half;
        const float inv = 1.0f / ol[reg];
        AO[obase + (size_t)qrow * kD + m]      = f32_bf16(o0[reg] * inv);
        AO[obase + (size_t)qrow * kD + 32 + m] = f32_bf16(o1[reg] * inv);
    }
}

}  // namespace

extern "C" void kernel_launch(void* const* d_in, const int* in_sizes, int n_in,
                              void* d_out, int out_size, void* d_ws, size_t ws_size,
                              hipStream_t stream)
{
    const float* q_in = (const float*)d_in[0];
    const float* k_in = (const float*)d_in[1];
    const float* v_in = (const float*)d_in[2];
    const float* Wq   = (const float*)d_in[3];
    const float* Wk   = (const float*)d_in[4];
    const float* Wv   = (const float*)d_in[5];
    const float* Wo   = (const float*)d_in[6];

    u16* ws = (u16*)d_ws;
    const size_t M1 = 1u << 20;
    u16* xq  = ws;             // later reused as Vt_g (dead after QKV GEMMs)
    u16* xk  = ws + 4 * M1;
    u16* xv  = ws + 8 * M1;
    u16* Wtq = ws + 12 * M1;
    u16* Wtk = ws + 13 * M1;
    u16* Wtv = ws + 14 * M1;
    u16* Wto = ws + 15 * M1;
    u16* Qp  = ws + 16 * M1;
    u16* Kp  = ws + 20 * M1;
    u16* Vp  = ws + 24 * M1;
    u16* AO  = ws + 28 * M1;
    u16* Vtg = xq;

    hipLaunchKernelGGL(prep, dim3(2048, 7), dim3(256), 0, stream,
                       q_in, k_in, v_in, xq, xk, xv,
                       Wq, Wk, Wv, Wo, Wtq, Wtk, Wtv, Wto);

    hipLaunchKernelGGL(gemm_qkv, dim3(8, 32, 3), dim3(256), 0, stream,
                       xq, xk, xv, Wtq, Wtk, Wtv, Qp, Kp, Vp);

    hipLaunchKernelGGL(vtrans, dim3(32, 32), dim3(256), 0, stream, Vp, Vtg);

    hipLaunchKernelGGL(attn, dim3(64, 32), dim3(64), 0, stream, Qp, Kp, Vtg, AO);

    hipLaunchKernelGGL(gemm_out, dim3(8, 64), dim3(256), 0, stream,
                       AO, Wto, (float*)d_out);
}

// Round 11
// 231.944 us; speedup vs baseline: 1.0892x; 1.0635x over previous
//
#include <hip/hip_runtime.h>

typedef unsigned short u16;
typedef short bf16x8 __attribute__((ext_vector_type(8)));
typedef float f32x4 __attribute__((ext_vector_type(4)));
typedef float f32x16 __attribute__((ext_vector_type(16)));

namespace {

constexpr int kB = 2, kS = 2048, kD = 1024, kH = 16, kDh = 64;
constexpr float kC2 = 0.125f * 1.44269504088896341f;  // score scale * log2(e)

__device__ inline u16 f32_bf16(float f) {
    unsigned u = __float_as_uint(f);
    u += 0x7FFFu + ((u >> 16) & 1u);        // RNE
    return (u16)(u >> 16);
}

__device__ inline u16 f32_bf16_fast(float f) {   // round-half-up (cheap)
    return (u16)((__float_as_uint(f) + 0x8000u) >> 16);
}

__device__ inline float fast_exp2(float x) {     // raw v_exp_f32 (1 instr)
    float r;
    asm("v_exp_f32 %0, %1" : "=v"(r) : "v"(x));
    return r;
}

__device__ inline void gl_lds16(const void* g, void* l) {
    __builtin_amdgcn_global_load_lds(
        (const __attribute__((address_space(1))) void*)g,
        (__attribute__((address_space(3))) void*)l, 16, 0, 0);
}

__device__ inline int swz8(int l) {   // GEMM staging swizzle (u16 units)
    return ((l & 3) ^ ((l >> 2) & 3) ^ ((l >> 4) & 3)) * 8;
}

// ------- fused prep: fp32->bf16 convert (y<3) + weight transpose (y>=3) ----
// Wq (z==0) pre-scaled by kC2 so attention scores arrive exp2-ready.
__global__ __launch_bounds__(256) void prep(
    const float* __restrict__ s0, const float* __restrict__ s1,
    const float* __restrict__ s2,
    u16* __restrict__ d0, u16* __restrict__ d1, u16* __restrict__ d2,
    const float* __restrict__ W0, const float* __restrict__ W1,
    const float* __restrict__ W2, const float* __restrict__ W3,
    u16* __restrict__ T0, u16* __restrict__ T1,
    u16* __restrict__ T2, u16* __restrict__ T3)
{
    const int y = blockIdx.y;
    if (y < 3) {
        const float* src = y == 0 ? s0 : (y == 1 ? s1 : s2);
        u16* dst = y == 0 ? d0 : (y == 1 ? d1 : d2);
        const int i = blockIdx.x * 256 + threadIdx.x;
        const float4* s4 = (const float4*)src;
        float4 a = s4[2 * i], b = s4[2 * i + 1];
        uint4 o;
        o.x = (unsigned)f32_bf16(a.x) | ((unsigned)f32_bf16(a.y) << 16);
        o.y = (unsigned)f32_bf16(a.z) | ((unsigned)f32_bf16(a.w) << 16);
        o.z = (unsigned)f32_bf16(b.x) | ((unsigned)f32_bf16(b.y) << 16);
        o.w = (unsigned)f32_bf16(b.z) | ((unsigned)f32_bf16(b.w) << 16);
        ((uint4*)dst)[i] = o;
        return;
    }
    if (blockIdx.x >= 256) return;
    const int z = y - 3;
    const float* W = z == 0 ? W0 : (z == 1 ? W1 : (z == 2 ? W2 : W3));
    u16* Wt = z == 0 ? T0 : (z == 1 ? T1 : (z == 2 ? T2 : T3));
    const float sc = (z == 0) ? kC2 : 1.0f;

    __shared__ __attribute__((aligned(16))) u16 T[64][65];  // [k][n]
    const int t = threadIdx.x;
    const int n0 = (blockIdx.x & 15) * 64, k0 = (blockIdx.x >> 4) * 64;
    const int r = t >> 4, c4 = (t & 15) * 4;
#pragma unroll
    for (int it = 0; it < 4; ++it) {
        const int rr = r + 16 * it;
        float4 v = *(const float4*)(W + (size_t)(k0 + rr) * kD + n0 + c4);
        T[rr][c4 + 0] = f32_bf16(v.x * sc);
        T[rr][c4 + 1] = f32_bf16(v.y * sc);
        T[rr][c4 + 2] = f32_bf16(v.z * sc);
        T[rr][c4 + 3] = f32_bf16(v.w * sc);
    }
    __syncthreads();
#pragma unroll
    for (int it = 0; it < 4; ++it) {
        const int nn = r + 16 * it;
        uint2 pk;
        pk.x = (unsigned)T[c4 + 0][nn] | ((unsigned)T[c4 + 1][nn] << 16);
        pk.y = (unsigned)T[c4 + 2][nn] | ((unsigned)T[c4 + 3][nn] << 16);
        *(uint2*)(Wt + (size_t)(n0 + nn) * kD + k0 + c4) = pk;
    }
}

// --------- V transpose (bf16): V[b,s,1024] -> Vt[bh=32][dh=64][s=2048] -----
__global__ __launch_bounds__(256) void vtrans(
    const u16* __restrict__ V, u16* __restrict__ Vt)
{
    __shared__ __attribute__((aligned(16))) u16 T[64][65];  // [d][s]
    const int t = threadIdx.x;
    const int s0 = blockIdx.x * 64;
    const int bh = blockIdx.y, b = bh >> 4, h = bh & 15;
    const int rr = t >> 3, c0 = (t & 7) * 8;
    union { u16 u[8]; uint4 v4; } buf;
#pragma unroll
    for (int p = 0; p < 2; ++p) {
        const int s = rr + 32 * p;
        buf.v4 = *(const uint4*)(V + (size_t)(b * kS + s0 + s) * kD + h * kDh + c0);
#pragma unroll
        for (int i = 0; i < 8; ++i) T[c0 + i][s] = buf.u[i];
    }
    __syncthreads();
#pragma unroll
    for (int p = 0; p < 2; ++p) {
        const int d = rr + 32 * p;
#pragma unroll
        for (int i = 0; i < 8; ++i) buf.u[i] = T[d][c0 + i];
        *(uint4*)(Vt + (size_t)(bh * kDh + d) * kS + s0 + c0) = buf.v4;
    }
}

// ---- m97-style bf16 MFMA GEMM: C[M,N] = A[M,K] @ Wt[N,K]^T, 128x128 tile --
template <bool F32OUT>
__device__ inline void gemm128_body(
    const u16* __restrict__ A, const u16* __restrict__ Wt,
    void* __restrict__ Cout, int M, int N, int K, int bx, int by)
{
    __shared__ __attribute__((aligned(16))) u16 As[128 * 32];
    __shared__ __attribute__((aligned(16))) u16 Bs[128 * 32];
    const int t = threadIdx.x, w = t >> 6, l = t & 63;
    const int quad = l >> 4, c = l & 15;
    const int wm = w >> 1, wn = w & 1;
    const int m0 = by * 128, n0 = bx * 128;
    const int lr = l >> 2, lc = swz8(l);
    const int xc = ((quad ^ (c & 3) ^ ((c >> 2) & 3))) * 8;

    const u16* ga0 = A  + (size_t)(m0 + w * 32 + lr) * K + lc;
    const u16* ga1 = A  + (size_t)(m0 + w * 32 + 16 + lr) * K + lc;
    const u16* gb0 = Wt + (size_t)(n0 + w * 32 + lr) * K + lc;
    const u16* gb1 = Wt + (size_t)(n0 + w * 32 + 16 + lr) * K + lc;
    u16* la0 = &As[(w * 32) * 32];
    u16* la1 = &As[(w * 32 + 16) * 32];
    u16* lb0 = &Bs[(w * 32) * 32];
    u16* lb1 = &Bs[(w * 32 + 16) * 32];

    f32x4 acc[4][4];
#pragma unroll
    for (int mi = 0; mi < 4; ++mi)
#pragma unroll
        for (int nj = 0; nj < 4; ++nj) acc[mi][nj] = 0;

    for (int k0 = 0; k0 < K; k0 += 32) {
        gl_lds16(ga0 + k0, la0);
        gl_lds16(ga1 + k0, la1);
        gl_lds16(gb0 + k0, lb0);
        gl_lds16(gb1 + k0, lb1);
        __syncthreads();
        bf16x8 af[4], bf[4];
#pragma unroll
        for (int mi = 0; mi < 4; ++mi)
            af[mi] = *(const bf16x8*)&As[(wm * 64 + mi * 16 + c) * 32 + xc];
#pragma unroll
        for (int nj = 0; nj < 4; ++nj)
            bf[nj] = *(const bf16x8*)&Bs[(wn * 64 + nj * 16 + c) * 32 + xc];
#pragma unroll
        for (int mi = 0; mi < 4; ++mi)
#pragma unroll
            for (int nj = 0; nj < 4; ++nj)
                acc[mi][nj] = __builtin_amdgcn_mfma_f32_16x16x32_bf16(
                    af[mi], bf[nj], acc[mi][nj], 0, 0, 0);
        __syncthreads();
    }

#pragma unroll
    for (int mi = 0; mi < 4; ++mi)
#pragma unroll
        for (int nj = 0; nj < 4; ++nj)
#pragma unroll
            for (int r = 0; r < 4; ++r) {
                const size_t row = m0 + wm * 64 + mi * 16 + quad * 4 + r;
                const size_t col = n0 + wn * 64 + nj * 16 + c;
                if (F32OUT)
                    ((float*)Cout)[row * N + col] = acc[mi][nj][r];
                else
                    ((u16*)Cout)[row * N + col] = f32_bf16(acc[mi][nj][r]);
            }
}

__global__ __launch_bounds__(256) void gemm_qkv(
    const u16* __restrict__ A0, const u16* __restrict__ A1,
    const u16* __restrict__ A2,
    const u16* __restrict__ W0, const u16* __restrict__ W1,
    const u16* __restrict__ W2,
    u16* __restrict__ C0, u16* __restrict__ C1, u16* __restrict__ C2)
{
    const int z = blockIdx.z;
    const u16* A  = z == 0 ? A0 : (z == 1 ? A1 : A2);
    const u16* Wt = z == 0 ? W0 : (z == 1 ? W1 : W2);
    u16* C = z == 0 ? C0 : (z == 1 ? C1 : C2);
    gemm128_body<false>(A, Wt, C, kB * kS, kD, kD, blockIdx.x, blockIdx.y);
}

// ---- 64x128-tile GEMM for the output projection (512 blocks = 2/CU) -------
__global__ __launch_bounds__(256) void gemm_out(
    const u16* __restrict__ A, const u16* __restrict__ Wt,
    float* __restrict__ C)
{
    __shared__ __attribute__((aligned(16))) u16 As[64 * 32];
    __shared__ __attribute__((aligned(16))) u16 Bs[128 * 32];
    const int N = kD, K = kD;
    const int t = threadIdx.x, w = t >> 6, l = t & 63;
    const int quad = l >> 4, c = l & 15;
    const int wm = w >> 1, wn = w & 1;
    const int m0 = blockIdx.y * 64, n0 = blockIdx.x * 128;
    const int lr = l >> 2, lc = swz8(l);
    const int xc = ((quad ^ (c & 3) ^ ((c >> 2) & 3))) * 8;

    const u16* ga  = A  + (size_t)(m0 + w * 16 + lr) * K + lc;
    const u16* gb0 = Wt + (size_t)(n0 + w * 16 + lr) * K + lc;
    const u16* gb1 = Wt + (size_t)(n0 + 64 + w * 16 + lr) * K + lc;
    u16* la  = &As[(w * 16) * 32];
    u16* lb0 = &Bs[(w * 16) * 32];
    u16* lb1 = &Bs[(64 + w * 16) * 32];

    f32x4 acc[2][4];
#pragma unroll
    for (int mi = 0; mi < 2; ++mi)
#pragma unroll
        for (int nj = 0; nj < 4; ++nj) acc[mi][nj] = 0;

    for (int k0 = 0; k0 < K; k0 += 32) {
        gl_lds16(ga + k0, la);
        gl_lds16(gb0 + k0, lb0);
        gl_lds16(gb1 + k0, lb1);
        __syncthreads();
        bf16x8 af[2], bf[4];
#pragma unroll
        for (int mi = 0; mi < 2; ++mi)
            af[mi] = *(const bf16x8*)&As[(wm * 32 + mi * 16 + c) * 32 + xc];
#pragma unroll
        for (int nj = 0; nj < 4; ++nj)
            bf[nj] = *(const bf16x8*)&Bs[(wn * 64 + nj * 16 + c) * 32 + xc];
#pragma unroll
        for (int mi = 0; mi < 2; ++mi)
#pragma unroll
            for (int nj = 0; nj < 4; ++nj)
                acc[mi][nj] = __builtin_amdgcn_mfma_f32_16x16x32_bf16(
                    af[mi], bf[nj], acc[mi][nj], 0, 0, 0);
        __syncthreads();
    }

#pragma unroll
    for (int mi = 0; mi < 2; ++mi)
#pragma unroll
        for (int nj = 0; nj < 4; ++nj)
#pragma unroll
            for (int r = 0; r < 4; ++r) {
                const size_t row = m0 + wm * 32 + mi * 16 + quad * 4 + r;
                const size_t col = n0 + wn * 64 + nj * 16 + c;
                C[row * N + col] = acc[mi][nj][r];
            }
}

// ------------- MFMA flash attention (R6 config: best measured, 69 µs) ------
// Block = 128 q-rows x (b,h); 4 waves, wave w owns q-rows w*32..+31.
// Single K/V buffer, staging SHARED across the 4 waves (1/4 tile each —
// minimizes LDS traffic per q-row; dbuf/VGPR pipelines measured worse).
// LDS rows 64 u16 (128 B); chunk XOR-swizzled by (row&7). Q pre-scaled by
// kC2 -> p = exp2(s) directly. Row-normalizer l via MFMA against ones.
__global__ __launch_bounds__(256) void attn(
    const u16* __restrict__ Q, const u16* __restrict__ K,
    const u16* __restrict__ Vt, u16* __restrict__ AO)
{
    __shared__ __attribute__((aligned(16))) u16 KsL[64 * 64];      // [key][dh]
    __shared__ __attribute__((aligned(16))) u16 VtL[64 * 64];      // [d][key]
    __shared__ __attribute__((aligned(16))) u16 Qs[4 * 32 * 64];   // per-wave [q][dh]
    __shared__ __attribute__((aligned(16))) u16 Ps[4 * 32 * 64];   // per-wave [q][key]

    const int t = threadIdx.x, w = t >> 6, l = t & 63;
    const int half = l >> 5, m = l & 31;      // fragment coords
    const int q0 = blockIdx.x * 128;
    const int bh = blockIdx.y, b = bh >> 4, h = bh & 15;
    const int sl = l >> 3;                    // staging row within 8-row group
    const int sc = (l & 7) ^ sl;              // staging global chunk (swizzled)

    // ---- stage Q (wave's 32 rows), swizzled
    const size_t qbase = (size_t)(b * kS + q0 + w * 32) * kD + h * kDh;
#pragma unroll
    for (int i = 0; i < 4; ++i)
        gl_lds16(Q + qbase + (size_t)(i * 8 + sl) * kD + sc * 8,
                 &Qs[w * 2048 + i * 512]);
    __syncthreads();

    bf16x8 qf[4];
#pragma unroll
    for (int ch = 0; ch < 4; ++ch)
        qf[ch] = *(const bf16x8*)
            &Qs[w * 2048 + m * 64 + ((2 * ch + half) ^ (m & 7)) * 8];

    bf16x8 ones;
#pragma unroll
    for (int i = 0; i < 8; ++i) ones[i] = (short)0x3F80;

    f32x16 o0 = 0, o1 = 0, ol = 0;

    const size_t kbase = (size_t)(b * kS) * kD + h * kDh;
    const size_t vbase = (size_t)bh * kDh * kS;

    for (int kt = 0; kt < kS / 64; ++kt) {
        // ---- stage K tile [key][dh] + Vt tile [d][key]; wave w rows w*16..+15
#pragma unroll
        for (int i = 0; i < 2; ++i) {
            const int R0 = w * 16 + i * 8;
            gl_lds16(K + kbase + (size_t)(kt * 64 + R0 + sl) * kD + sc * 8,
                     &KsL[R0 * 64]);
            gl_lds16(Vt + vbase + (size_t)(R0 + sl) * kS + kt * 64 + sc * 8,
                     &VtL[R0 * 64]);
        }
        __syncthreads();

        // ---- S = Qc2 K^T : two 32x32 key-subtiles, 4 k-chains each
        f32x16 s0 = 0, s1 = 0;
#pragma unroll
        for (int ch = 0; ch < 4; ++ch) {
            const int xo = ((2 * ch + half) ^ (m & 7)) * 8;
            const bf16x8 kf0 = *(const bf16x8*)&KsL[(m) * 64 + xo];
            const bf16x8 kf1 = *(const bf16x8*)&KsL[(32 + m) * 64 + xo];
            s0 = __builtin_amdgcn_mfma_f32_32x32x16_bf16(qf[ch], kf0, s0, 0, 0, 0);
            s1 = __builtin_amdgcn_mfma_f32_32x32x16_bf16(qf[ch], kf1, s1, 0, 0, 0);
        }

        // ---- p = exp2(s) -> bf16 -> Ps[q][key] (swizzled, wave-private)
#pragma unroll
        for (int reg = 0; reg < 16; ++reg) {
            const int qrow = (reg & 3) + 8 * (reg >> 2) + 4 * half;
            const int base = w * 2048 + qrow * 64;
            const int sw = (qrow & 7);
            {
                const int key = m;               // subtile 0
                Ps[base + ((key >> 3) ^ sw) * 8 + (key & 7)] =
                    f32_bf16_fast(fast_exp2(s0[reg]));
            }
            {
                const int key = 32 + m;          // subtile 1
                Ps[base + ((key >> 3) ^ sw) * 8 + (key & 7)] =
                    f32_bf16_fast(fast_exp2(s1[reg]));
            }
        }

        // ---- O += P @ V ; l += P @ ones   (Ps wave-private: no barrier)
#pragma unroll
        for (int ch = 0; ch < 4; ++ch) {
            const int xo = ((2 * ch + half) ^ (m & 7)) * 8;
            const bf16x8 pf = *(const bf16x8*)&Ps[w * 2048 + m * 64 + xo];
            const bf16x8 vf0 = *(const bf16x8*)&VtL[(m) * 64 + xo];
            const bf16x8 vf1 = *(const bf16x8*)&VtL[(32 + m) * 64 + xo];
            o0 = __builtin_amdgcn_mfma_f32_32x32x16_bf16(pf, vf0, o0, 0, 0, 0);
            o1 = __builtin_amdgcn_mfma_f32_32x32x16_bf16(pf, vf1, o1, 0, 0, 0);
            ol = __builtin_amdgcn_mfma_f32_32x32x16_bf16(pf, ones, ol, 0, 0, 0);
        }
        __syncthreads();
    }

    // ---- epilogue: O/l -> bf16 AO[b,s,1024]
    const size_t obase = (size_t)(b * kS + q0 + w * 32) * kD + h * kDh;
#pragma unroll
    for (int reg = 0; reg < 16; ++reg) {
        const int qrow = (reg & 3) + 8 * (reg >> 2) + 4 * half;
        const float inv = 1.0f / ol[reg];
        AO[obase + (size_t)qrow * kD + m]      = f32_bf16(o0[reg] * inv);
        AO[obase + (size_t)qrow * kD + 32 + m] = f32_bf16(o1[reg] * inv);
    }
}

}  // namespace

extern "C" void kernel_launch(void* const* d_in, const int* in_sizes, int n_in,
                              void* d_out, int out_size, void* d_ws, size_t ws_size,
                              hipStream_t stream)
{
    const float* q_in = (const float*)d_in[0];
    const float* k_in = (const float*)d_in[1];
    const float* v_in = (const float*)d_in[2];
    const float* Wq   = (const float*)d_in[3];
    const float* Wk   = (const float*)d_in[4];
    const float* Wv   = (const float*)d_in[5];
    const float* Wo   = (const float*)d_in[6];

    u16* ws = (u16*)d_ws;
    const size_t M1 = 1u << 20;
    u16* xq  = ws;             // later reused as Vt_g (dead after QKV GEMMs)
    u16* xk  = ws + 4 * M1;
    u16* xv  = ws + 8 * M1;
    u16* Wtq = ws + 12 * M1;
    u16* Wtk = ws + 13 * M1;
    u16* Wtv = ws + 14 * M1;
    u16* Wto = ws + 15 * M1;
    u16* Qp  = ws + 16 * M1;
    u16* Kp  = ws + 20 * M1;
    u16* Vp  = ws + 24 * M1;
    u16* AO  = ws + 28 * M1;
    u16* Vtg = xq;

    hipLaunchKernelGGL(prep, dim3(2048, 7), dim3(256), 0, stream,
                       q_in, k_in, v_in, xq, xk, xv,
                       Wq, Wk, Wv, Wo, Wtq, Wtk, Wtv, Wto);

    hipLaunchKernelGGL(gemm_qkv, dim3(8, 32, 3), dim3(256), 0, stream,
                       xq, xk, xv, Wtq, Wtk, Wtv, Qp, Kp, Vp);

    hipLaunchKernelGGL(vtrans, dim3(32, 32), dim3(256), 0, stream, Vp, Vtg);

    hipLaunchKernelGGL(attn, dim3(16, 32), dim3(256), 0, stream, Qp, Kp, Vtg, AO);

    hipLaunchKernelGGL(gemm_out, dim3(8, 64), dim3(256), 0, stream,
                       AO, Wto, (float*)d_out);
}

// Round 12
// 223.391 us; speedup vs baseline: 1.1309x; 1.0383x over previous
//
#include <hip/hip_runtime.h>

typedef unsigned short u16;
typedef short bf16x8 __attribute__((ext_vector_type(8)));
typedef float f32x4 __attribute__((ext_vector_type(4)));
typedef float f32x16 __attribute__((ext_vector_type(16)));

namespace {

constexpr int kB = 2, kS = 2048, kD = 1024, kH = 16, kDh = 64;
constexpr float kC2 = 0.125f * 1.44269504088896341f;  // score scale * log2(e)

__device__ inline u16 f32_bf16(float f) {
    unsigned u = __float_as_uint(f);
    u += 0x7FFFu + ((u >> 16) & 1u);        // RNE
    return (u16)(u >> 16);
}

__device__ inline u16 f32_bf16_fast(float f) {   // round-half-up (cheap)
    return (u16)((__float_as_uint(f) + 0x8000u) >> 16);
}

__device__ inline float fast_exp2(float x) {     // raw v_exp_f32 (1 instr)
    float r;
    asm("v_exp_f32 %0, %1" : "=v"(r) : "v"(x));
    return r;
}

__device__ inline void gl_lds16(const void* g, void* l) {
    __builtin_amdgcn_global_load_lds(
        (const __attribute__((address_space(1))) void*)g,
        (__attribute__((address_space(3))) void*)l, 16, 0, 0);
}

__device__ inline int swz8(int l) {   // GEMM staging swizzle (u16 units)
    return ((l & 3) ^ ((l >> 2) & 3) ^ ((l >> 4) & 3)) * 8;
}

// ------- fused prep: fp32->bf16 convert (y<3) + weight transpose (y>=3) ----
// Wq (z==0) pre-scaled by kC2 so attention scores arrive exp2-ready.
__global__ __launch_bounds__(256) void prep(
    const float* __restrict__ s0, const float* __restrict__ s1,
    const float* __restrict__ s2,
    u16* __restrict__ d0, u16* __restrict__ d1, u16* __restrict__ d2,
    const float* __restrict__ W0, const float* __restrict__ W1,
    const float* __restrict__ W2, const float* __restrict__ W3,
    u16* __restrict__ T0, u16* __restrict__ T1,
    u16* __restrict__ T2, u16* __restrict__ T3)
{
    const int y = blockIdx.y;
    if (y < 3) {
        const float* src = y == 0 ? s0 : (y == 1 ? s1 : s2);
        u16* dst = y == 0 ? d0 : (y == 1 ? d1 : d2);
        const int i = blockIdx.x * 256 + threadIdx.x;
        const float4* s4 = (const float4*)src;
        float4 a = s4[2 * i], b = s4[2 * i + 1];
        uint4 o;
        o.x = (unsigned)f32_bf16(a.x) | ((unsigned)f32_bf16(a.y) << 16);
        o.y = (unsigned)f32_bf16(a.z) | ((unsigned)f32_bf16(a.w) << 16);
        o.z = (unsigned)f32_bf16(b.x) | ((unsigned)f32_bf16(b.y) << 16);
        o.w = (unsigned)f32_bf16(b.z) | ((unsigned)f32_bf16(b.w) << 16);
        ((uint4*)dst)[i] = o;
        return;
    }
    if (blockIdx.x >= 256) return;
    const int z = y - 3;
    const float* W = z == 0 ? W0 : (z == 1 ? W1 : (z == 2 ? W2 : W3));
    u16* Wt = z == 0 ? T0 : (z == 1 ? T1 : (z == 2 ? T2 : T3));
    const float sc = (z == 0) ? kC2 : 1.0f;

    __shared__ __attribute__((aligned(16))) u16 T[64][65];  // [k][n]
    const int t = threadIdx.x;
    const int n0 = (blockIdx.x & 15) * 64, k0 = (blockIdx.x >> 4) * 64;
    const int r = t >> 4, c4 = (t & 15) * 4;
#pragma unroll
    for (int it = 0; it < 4; ++it) {
        const int rr = r + 16 * it;
        float4 v = *(const float4*)(W + (size_t)(k0 + rr) * kD + n0 + c4);
        T[rr][c4 + 0] = f32_bf16(v.x * sc);
        T[rr][c4 + 1] = f32_bf16(v.y * sc);
        T[rr][c4 + 2] = f32_bf16(v.z * sc);
        T[rr][c4 + 3] = f32_bf16(v.w * sc);
    }
    __syncthreads();
#pragma unroll
    for (int it = 0; it < 4; ++it) {
        const int nn = r + 16 * it;
        uint2 pk;
        pk.x = (unsigned)T[c4 + 0][nn] | ((unsigned)T[c4 + 1][nn] << 16);
        pk.y = (unsigned)T[c4 + 2][nn] | ((unsigned)T[c4 + 3][nn] << 16);
        *(uint2*)(Wt + (size_t)(n0 + nn) * kD + k0 + c4) = pk;
    }
}

// --------- V transpose (bf16): V[b,s,1024] -> Vt[bh=32][dh=64][s=2048] -----
__global__ __launch_bounds__(256) void vtrans(
    const u16* __restrict__ V, u16* __restrict__ Vt)
{
    __shared__ __attribute__((aligned(16))) u16 T[64][65];  // [d][s]
    const int t = threadIdx.x;
    const int s0 = blockIdx.x * 64;
    const int bh = blockIdx.y, b = bh >> 4, h = bh & 15;
    const int rr = t >> 3, c0 = (t & 7) * 8;
    union { u16 u[8]; uint4 v4; } buf;
#pragma unroll
    for (int p = 0; p < 2; ++p) {
        const int s = rr + 32 * p;
        buf.v4 = *(const uint4*)(V + (size_t)(b * kS + s0 + s) * kD + h * kDh + c0);
#pragma unroll
        for (int i = 0; i < 8; ++i) T[c0 + i][s] = buf.u[i];
    }
    __syncthreads();
#pragma unroll
    for (int p = 0; p < 2; ++p) {
        const int d = rr + 32 * p;
#pragma unroll
        for (int i = 0; i < 8; ++i) buf.u[i] = T[d][c0 + i];
        *(uint4*)(Vt + (size_t)(bh * kDh + d) * kS + s0 + c0) = buf.v4;
    }
}

// ---- m97-style bf16 MFMA GEMM: C[M,N] = A[M,K] @ Wt[N,K]^T, 128x128 tile --
template <bool F32OUT>
__device__ inline void gemm128_body(
    const u16* __restrict__ A, const u16* __restrict__ Wt,
    void* __restrict__ Cout, int M, int N, int K, int bx, int by)
{
    __shared__ __attribute__((aligned(16))) u16 As[128 * 32];
    __shared__ __attribute__((aligned(16))) u16 Bs[128 * 32];
    const int t = threadIdx.x, w = t >> 6, l = t & 63;
    const int quad = l >> 4, c = l & 15;
    const int wm = w >> 1, wn = w & 1;
    const int m0 = by * 128, n0 = bx * 128;
    const int lr = l >> 2, lc = swz8(l);
    const int xc = ((quad ^ (c & 3) ^ ((c >> 2) & 3))) * 8;

    const u16* ga0 = A  + (size_t)(m0 + w * 32 + lr) * K + lc;
    const u16* ga1 = A  + (size_t)(m0 + w * 32 + 16 + lr) * K + lc;
    const u16* gb0 = Wt + (size_t)(n0 + w * 32 + lr) * K + lc;
    const u16* gb1 = Wt + (size_t)(n0 + w * 32 + 16 + lr) * K + lc;
    u16* la0 = &As[(w * 32) * 32];
    u16* la1 = &As[(w * 32 + 16) * 32];
    u16* lb0 = &Bs[(w * 32) * 32];
    u16* lb1 = &Bs[(w * 32 + 16) * 32];

    f32x4 acc[4][4];
#pragma unroll
    for (int mi = 0; mi < 4; ++mi)
#pragma unroll
        for (int nj = 0; nj < 4; ++nj) acc[mi][nj] = 0;

    for (int k0 = 0; k0 < K; k0 += 32) {
        gl_lds16(ga0 + k0, la0);
        gl_lds16(ga1 + k0, la1);
        gl_lds16(gb0 + k0, lb0);
        gl_lds16(gb1 + k0, lb1);
        __syncthreads();
        bf16x8 af[4], bf[4];
#pragma unroll
        for (int mi = 0; mi < 4; ++mi)
            af[mi] = *(const bf16x8*)&As[(wm * 64 + mi * 16 + c) * 32 + xc];
#pragma unroll
        for (int nj = 0; nj < 4; ++nj)
            bf[nj] = *(const bf16x8*)&Bs[(wn * 64 + nj * 16 + c) * 32 + xc];
#pragma unroll
        for (int mi = 0; mi < 4; ++mi)
#pragma unroll
            for (int nj = 0; nj < 4; ++nj)
                acc[mi][nj] = __builtin_amdgcn_mfma_f32_16x16x32_bf16(
                    af[mi], bf[nj], acc[mi][nj], 0, 0, 0);
        __syncthreads();
    }

#pragma unroll
    for (int mi = 0; mi < 4; ++mi)
#pragma unroll
        for (int nj = 0; nj < 4; ++nj)
#pragma unroll
            for (int r = 0; r < 4; ++r) {
                const size_t row = m0 + wm * 64 + mi * 16 + quad * 4 + r;
                const size_t col = n0 + wn * 64 + nj * 16 + c;
                if (F32OUT)
                    ((float*)Cout)[row * N + col] = acc[mi][nj][r];
                else
                    ((u16*)Cout)[row * N + col] = f32_bf16(acc[mi][nj][r]);
            }
}

__global__ __launch_bounds__(256) void gemm_qkv(
    const u16* __restrict__ A0, const u16* __restrict__ A1,
    const u16* __restrict__ A2,
    const u16* __restrict__ W0, const u16* __restrict__ W1,
    const u16* __restrict__ W2,
    u16* __restrict__ C0, u16* __restrict__ C1, u16* __restrict__ C2)
{
    const int z = blockIdx.z;
    const u16* A  = z == 0 ? A0 : (z == 1 ? A1 : A2);
    const u16* Wt = z == 0 ? W0 : (z == 1 ? W1 : W2);
    u16* C = z == 0 ? C0 : (z == 1 ? C1 : C2);
    gemm128_body<false>(A, Wt, C, kB * kS, kD, kD, blockIdx.x, blockIdx.y);
}

// ---- 64x128-tile GEMM for the output projection (512 blocks = 2/CU) -------
__global__ __launch_bounds__(256) void gemm_out(
    const u16* __restrict__ A, const u16* __restrict__ Wt,
    float* __restrict__ C)
{
    __shared__ __attribute__((aligned(16))) u16 As[64 * 32];
    __shared__ __attribute__((aligned(16))) u16 Bs[128 * 32];
    const int N = kD, K = kD;
    const int t = threadIdx.x, w = t >> 6, l = t & 63;
    const int quad = l >> 4, c = l & 15;
    const int wm = w >> 1, wn = w & 1;
    const int m0 = blockIdx.y * 64, n0 = blockIdx.x * 128;
    const int lr = l >> 2, lc = swz8(l);
    const int xc = ((quad ^ (c & 3) ^ ((c >> 2) & 3))) * 8;

    const u16* ga  = A  + (size_t)(m0 + w * 16 + lr) * K + lc;
    const u16* gb0 = Wt + (size_t)(n0 + w * 16 + lr) * K + lc;
    const u16* gb1 = Wt + (size_t)(n0 + 64 + w * 16 + lr) * K + lc;
    u16* la  = &As[(w * 16) * 32];
    u16* lb0 = &Bs[(w * 16) * 32];
    u16* lb1 = &Bs[(64 + w * 16) * 32];

    f32x4 acc[2][4];
#pragma unroll
    for (int mi = 0; mi < 2; ++mi)
#pragma unroll
        for (int nj = 0; nj < 4; ++nj) acc[mi][nj] = 0;

    for (int k0 = 0; k0 < K; k0 += 32) {
        gl_lds16(ga + k0, la);
        gl_lds16(gb0 + k0, lb0);
        gl_lds16(gb1 + k0, lb1);
        __syncthreads();
        bf16x8 af[2], bf[4];
#pragma unroll
        for (int mi = 0; mi < 2; ++mi)
            af[mi] = *(const bf16x8*)&As[(wm * 32 + mi * 16 + c) * 32 + xc];
#pragma unroll
        for (int nj = 0; nj < 4; ++nj)
            bf[nj] = *(const bf16x8*)&Bs[(wn * 64 + nj * 16 + c) * 32 + xc];
#pragma unroll
        for (int mi = 0; mi < 2; ++mi)
#pragma unroll
            for (int nj = 0; nj < 4; ++nj)
                acc[mi][nj] = __builtin_amdgcn_mfma_f32_16x16x32_bf16(
                    af[mi], bf[nj], acc[mi][nj], 0, 0, 0);
        __syncthreads();
    }

#pragma unroll
    for (int mi = 0; mi < 2; ++mi)
#pragma unroll
        for (int nj = 0; nj < 4; ++nj)
#pragma unroll
            for (int r = 0; r < 4; ++r) {
                const size_t row = m0 + wm * 32 + mi * 16 + quad * 4 + r;
                const size_t col = n0 + wn * 64 + nj * 16 + c;
                C[row * N + col] = acc[mi][nj][r];
            }
}

// ------------- MFMA flash attention: distinct-symbol double buffer ---------
// R6 structure (4 waves x 32 q-rows, shared staging, 2 barriers/tile) but
// K/V double-buffered into FOUR DISTINCT __shared__ symbols with a 2x-unrolled
// key loop, so LLVM alias analysis can prove gl_lds(->B) never aliases
// ds_read(A): the vmcnt drain at each barrier then finds the prefetch already
// landed (it was issued a full compute phase earlier). This is the fix for
// R8's regression, where indexed KsL[2][..] forced a conservative early wait.
__global__ __launch_bounds__(256) void attn(
    const u16* __restrict__ Q, const u16* __restrict__ K,
    const u16* __restrict__ Vt, u16* __restrict__ AO)
{
    __shared__ __attribute__((aligned(16))) u16 KsA[64 * 64];      // [key][dh]
    __shared__ __attribute__((aligned(16))) u16 KsB[64 * 64];
    __shared__ __attribute__((aligned(16))) u16 VtA[64 * 64];      // [d][key]
    __shared__ __attribute__((aligned(16))) u16 VtB[64 * 64];
    __shared__ __attribute__((aligned(16))) u16 Qs[4 * 32 * 64];   // per-wave [q][dh]
    __shared__ __attribute__((aligned(16))) u16 Ps[4 * 32 * 64];   // per-wave [q][key]

    const int t = threadIdx.x, w = t >> 6, l = t & 63;
    const int half = l >> 5, m = l & 31;      // fragment coords
    const int q0 = blockIdx.x * 128;
    const int bh = blockIdx.y, b = bh >> 4, h = bh & 15;
    const int sl = l >> 3;                    // staging row within 8-row group
    const int sc = (l & 7) ^ sl;              // staging global chunk (swizzled)

    const size_t kbase = (size_t)(b * kS) * kD + h * kDh;
    const size_t vbase = (size_t)bh * kDh * kS;
    const size_t qbase = (size_t)(b * kS + q0 + w * 32) * kD + h * kDh;

    // stage one K/V tile (wave w covers rows w*16..w*16+15 of the 64)
    auto stage = [&](int kt, u16* KsP, u16* VtP) {
#pragma unroll
        for (int i = 0; i < 2; ++i) {
            const int R0 = w * 16 + i * 8;
            gl_lds16(K + kbase + (size_t)(kt * 64 + R0 + sl) * kD + sc * 8,
                     &KsP[R0 * 64]);
            gl_lds16(Vt + vbase + (size_t)(R0 + sl) * kS + kt * 64 + sc * 8,
                     &VtP[R0 * 64]);
        }
    };

    // ---- prologue: Q + tile 0 into A
#pragma unroll
    for (int i = 0; i < 4; ++i)
        gl_lds16(Q + qbase + (size_t)(i * 8 + sl) * kD + sc * 8,
                 &Qs[w * 2048 + i * 512]);
    stage(0, KsA, VtA);
    __syncthreads();

    bf16x8 qf[4];
#pragma unroll
    for (int ch = 0; ch < 4; ++ch)
        qf[ch] = *(const bf16x8*)
            &Qs[w * 2048 + m * 64 + ((2 * ch + half) ^ (m & 7)) * 8];

    bf16x8 ones;
#pragma unroll
    for (int i = 0; i < 8; ++i) ones[i] = (short)0x3F80;

    f32x16 o0 = 0, o1 = 0, ol = 0;

    // compute one key tile from the given buffers (Ps is wave-private)
    auto compute = [&](const u16* KsP, const u16* VtP) {
        f32x16 s0 = 0, s1 = 0;
#pragma unroll
        for (int ch = 0; ch < 4; ++ch) {
            const int xo = ((2 * ch + half) ^ (m & 7)) * 8;
            const bf16x8 kf0 = *(const bf16x8*)&KsP[(m) * 64 + xo];
            const bf16x8 kf1 = *(const bf16x8*)&KsP[(32 + m) * 64 + xo];
            s0 = __builtin_amdgcn_mfma_f32_32x32x16_bf16(qf[ch], kf0, s0, 0, 0, 0);
            s1 = __builtin_amdgcn_mfma_f32_32x32x16_bf16(qf[ch], kf1, s1, 0, 0, 0);
        }
#pragma unroll
        for (int reg = 0; reg < 16; ++reg) {
            const int qrow = (reg & 3) + 8 * (reg >> 2) + 4 * half;
            const int base = w * 2048 + qrow * 64;
            const int sw = (qrow & 7);
            {
                const int key = m;               // subtile 0
                Ps[base + ((key >> 3) ^ sw) * 8 + (key & 7)] =
                    f32_bf16_fast(fast_exp2(s0[reg]));
            }
            {
                const int key = 32 + m;          // subtile 1
                Ps[base + ((key >> 3) ^ sw) * 8 + (key & 7)] =
                    f32_bf16_fast(fast_exp2(s1[reg]));
            }
        }
#pragma unroll
        for (int ch = 0; ch < 4; ++ch) {
            const int xo = ((2 * ch + half) ^ (m & 7)) * 8;
            const bf16x8 pf = *(const bf16x8*)&Ps[w * 2048 + m * 64 + xo];
            const bf16x8 vf0 = *(const bf16x8*)&VtP[(m) * 64 + xo];
            const bf16x8 vf1 = *(const bf16x8*)&VtP[(32 + m) * 64 + xo];
            o0 = __builtin_amdgcn_mfma_f32_32x32x16_bf16(pf, vf0, o0, 0, 0, 0);
            o1 = __builtin_amdgcn_mfma_f32_32x32x16_bf16(pf, vf1, o1, 0, 0, 0);
            ol = __builtin_amdgcn_mfma_f32_32x32x16_bf16(pf, ones, ol, 0, 0, 0);
        }
    };

    constexpr int NT = kS / 64;   // 32, even
#pragma unroll 1
    for (int kt = 0; kt < NT; kt += 2) {
        if (kt + 1 < NT) stage(kt + 1, KsB, VtB);   // prefetch into B
        compute(KsA, VtA);
        __syncthreads();   // everyone done reading A; B landed during compute
        if (kt + 2 < NT) stage(kt + 2, KsA, VtA);   // prefetch into A
        compute(KsB, VtB);
        __syncthreads();   // everyone done reading B; A landed during compute
    }

    // ---- epilogue: O/l -> bf16 AO[b,s,1024]
    const size_t obase = (size_t)(b * kS + q0 + w * 32) * kD + h * kDh;
#pragma unroll
    for (int reg = 0; reg < 16; ++reg) {
        const int qrow = (reg & 3) + 8 * (reg >> 2) + 4 * half;
        const float inv = 1.0f / ol[reg];
        AO[obase + (size_t)qrow * kD + m]      = f32_bf16(o0[reg] * inv);
        AO[obase + (size_t)qrow * kD + 32 + m] = f32_bf16(o1[reg] * inv);
    }
}

}  // namespace

extern "C" void kernel_launch(void* const* d_in, const int* in_sizes, int n_in,
                              void* d_out, int out_size, void* d_ws, size_t ws_size,
                              hipStream_t stream)
{
    const float* q_in = (const float*)d_in[0];
    const float* k_in = (const float*)d_in[1];
    const float* v_in = (const float*)d_in[2];
    const float* Wq   = (const float*)d_in[3];
    const float* Wk   = (const float*)d_in[4];
    const float* Wv   = (const float*)d_in[5];
    const float* Wo   = (const float*)d_in[6];

    u16* ws = (u16*)d_ws;
    const size_t M1 = 1u << 20;
    u16* xq  = ws;             // later reused as Vt_g (dead after QKV GEMMs)
    u16* xk  = ws + 4 * M1;
    u16* xv  = ws + 8 * M1;
    u16* Wtq = ws + 12 * M1;
    u16* Wtk = ws + 13 * M1;
    u16* Wtv = ws + 14 * M1;
    u16* Wto = ws + 15 * M1;
    u16* Qp  = ws + 16 * M1;
    u16* Kp  = ws + 20 * M1;
    u16* Vp  = ws + 24 * M1;
    u16* AO  = ws + 28 * M1;
    u16* Vtg = xq;

    hipLaunchKernelGGL(prep, dim3(2048, 7), dim3(256), 0, stream,
                       q_in, k_in, v_in, xq, xk, xv,
                       Wq, Wk, Wv, Wo, Wtq, Wtk, Wtv, Wto);

    hipLaunchKernelGGL(gemm_qkv, dim3(8, 32, 3), dim3(256), 0, stream,
                       xq, xk, xv, Wtq, Wtk, Wtv, Qp, Kp, Vp);

    hipLaunchKernelGGL(vtrans, dim3(32, 32), dim3(256), 0, stream, Vp, Vtg);

    hipLaunchKernelGGL(attn, dim3(16, 32), dim3(256), 0, stream, Qp, Kp, Vtg, AO);

    hipLaunchKernelGGL(gemm_out, dim3(8, 64), dim3(256), 0, stream,
                       AO, Wto, (float*)d_out);
}